// Round 7
// baseline (239.021 us; speedup 1.0000x reference)
//
#include <hip/hip_runtime.h>
#include <hip/hip_bf16.h>

#define NN 50000
#define EE 800000
#define NEG 0.2f
#define NS (NN*8)        // scan length: (node, shard) pairs
#define NSB 391          // scan blocks: ceil(400000/1024)

using u32 = unsigned int;
typedef short short4v __attribute__((ext_vector_type(4)));
typedef float f32x4 __attribute__((ext_vector_type(4)));

__device__ __forceinline__ unsigned short f2bf(float f){
  u32 b = __float_as_uint(f);
  b += 0x7FFFu + ((b >> 16) & 1u);        // RNE; inputs finite
  return (unsigned short)(b >> 16);
}

// ---- K0: merged precompute ----
// blocks 0..127 : WzT[n][k] (bf16) where Wz = W_gat @ blockdiag(W_c[0:64]); row k = bid
// block 128     : Wt[16][4], cvec[64] (ns-pool@W_c + b_gat@W_c + b_c folded)
// block 129     : avp[8][64] packed bf16 B-fragments (cols 0-3 src heads, 4-7 dst heads)
__global__ __launch_bounds__(256) void k_pre_all(
        const float* __restrict__ Wg, const float* __restrict__ W_c,
        const float* __restrict__ W_edge, const float* __restrict__ att_edge,
        const float* __restrict__ b_c, const float* __restrict__ ns,
        const float* __restrict__ b_gat,
        const float* __restrict__ att_src, const float* __restrict__ att_dst,
        unsigned short* __restrict__ WzT, float* __restrict__ Wt,
        float* __restrict__ cvec, uint2* __restrict__ avp){
  int bid = blockIdx.x, tid = threadIdx.x;
  if (bid < 128){
    __shared__ float sWg[256];
    __shared__ float sWc[64*64];
    sWg[tid] = Wg[bid*256 + tid];
    for (int i = tid; i < 4096; i += 256) sWc[i] = W_c[i];
    __syncthreads();
    int h = tid >> 6, j = tid & 63;
    float s = 0.f;
    #pragma unroll 8
    for (int c = 0; c < 64; c++) s += sWg[h*64 + c] * sWc[c*64 + j];
    WzT[tid*128 + bid] = f2bf(s);      // transposed bf16 store
  } else if (bid == 128){
    if (tid < 64){
      int d = tid >> 2, h = tid & 3;
      float s = 0.f;
      for (int c = 0; c < 64; c++) s += W_edge[d*256 + h*64 + c] * att_edge[h*64 + c];
      Wt[d*4 + h] = s;
    } else if (tid < 128){
      int j = tid - 64;
      float s = b_c[j];
      for (int d = 0; d < 16; d++) s += ns[d >> 1] * W_c[(64 + d)*64 + j];
      for (int c = 0; c < 64; c++) s += b_gat[c] * W_c[c*64 + j];
      cvec[j] = s;
    }
  } else {
    __shared__ float sav2[1024];       // [k][o] o: 0-3 src, 4-7 dst
    for (int i = tid; i < 1024; i += 256){
      int k = i >> 3, o = i & 7, h = o & 3;
      const float* att = (o < 4) ? att_src : att_dst;
      float s = 0.f;
      for (int c = 0; c < 64; c++) s += Wg[k*256 + h*64 + c] * att[h*64 + c];
      sav2[i] = s;
    }
    __syncthreads();
    if (tid < 64){
      int l = tid, lg = l >> 4, lr = l & 15;
      for (int ks = 0; ks < 8; ks++){
        unsigned int h0, h1, h2, h3;
        int kb = ks*16 + lg*4;
        h0 = (lr < 8) ? f2bf(sav2[(kb+0)*8 + lr]) : 0u;
        h1 = (lr < 8) ? f2bf(sav2[(kb+1)*8 + lr]) : 0u;
        h2 = (lr < 8) ? f2bf(sav2[(kb+2)*8 + lr]) : 0u;
        h3 = (lr < 8) ? f2bf(sav2[(kb+3)*8 + lr]) : 0u;
        uint2 u; u.x = h0 | (h1 << 16); u.y = h2 | (h3 << 16);
        avp[ks*64 + l] = u;
      }
    }
  }
}

// ---- K_deg: 8-way sharded degree histogram + per-edge rank capture ----
// shard = blockIdx&7 (uniform per block); deg8 is SHARD-MAJOR so concurrent
// shards hit disjoint cache-line regions (8x fewer RMWs per line).
__global__ __launch_bounds__(256) void k_deg(const int* __restrict__ dsts,
        u32* __restrict__ deg8, unsigned short* __restrict__ rank){
  int g = blockIdx.x*256 + threadIdx.x;   // group of 4 edges
  if (g*4 >= EE) return;
  int shard = blockIdx.x & 7;             // == (e>>10)&7 for all 4 edges
  u32* dg = deg8 + (size_t)shard*NN;
  int4 d4 = *(const int4*)(dsts + (size_t)g*4);
  u32 r0 = atomicAdd(&dg[d4.x], 1u);
  u32 r1 = atomicAdd(&dg[d4.y], 1u);
  u32 r2 = atomicAdd(&dg[d4.z], 1u);
  u32 r3 = atomicAdd(&dg[d4.w], 1u);
  uint2 pk;
  pk.x = (r0 & 0xffffu) | (r1 << 16);
  pk.y = (r2 & 0xffffu) | (r3 << 16);
  *(uint2*)(rank + (size_t)g*4) = pk;
}

// ---- K1: zs = x @ Wz via MFMA + fused a_src/a_dst MFMA. Zero atomics/barriers. ----
__global__ __launch_bounds__(256) void k_gemm(const float* __restrict__ x,
        const unsigned short* __restrict__ WzT, const uint2* __restrict__ avp,
        __hip_bfloat16* __restrict__ zs,
        float* __restrict__ a_src, float* __restrict__ a_dst){
  __shared__ alignas(16) __hip_bfloat16 zt[4][16][264];   // per-wave private
  int tid = threadIdx.x;
  int w = tid >> 6, l = tid & 63;
  int lr = l & 15, lg = l >> 4;
  int n0 = blockIdx.x * 64 + w*16;     // wave's 16 rows

  // A-fragments (8 K-steps of 16) + fused adot MFMA
  short4v afr[8];
  f32x4 cad = {0.f, 0.f, 0.f, 0.f};
  #pragma unroll
  for (int ks = 0; ks < 8; ks++){
    int row = n0 + lr; if (row >= NN) row = NN - 1;
    float4 xa = *(const float4*)(x + (size_t)row*128 + ks*16 + lg*4);
    short4v a;
    a[0] = (short)f2bf(xa.x); a[1] = (short)f2bf(xa.y);
    a[2] = (short)f2bf(xa.z); a[3] = (short)f2bf(xa.w);
    afr[ks] = a;
    uint2 bv = avp[ks*64 + l];
    short4v b = __builtin_bit_cast(short4v, bv);
    cad = __builtin_amdgcn_mfma_f32_16x16x16bf16_1k(afr[ks], b, cad, 0, 0, 0);
  }
  #pragma unroll
  for (int r = 0; r < 4; r++){
    int n = n0 + lg*4 + r;
    if (n < NN){
      if (lr < 4)      a_src[(size_t)n*4 + lr]       = cad[r];
      else if (lr < 8) a_dst[(size_t)n*4 + (lr - 4)] = cad[r];
    }
  }

  // main GEMM: 16 column-tiles of 16, B-frags from L2-resident WzT (64KB)
  #pragma unroll 2
  for (int t = 0; t < 16; t++){
    f32x4 c = {0.f, 0.f, 0.f, 0.f};
    #pragma unroll
    for (int ks = 0; ks < 8; ks++){
      short4v b = *(const short4v*)(WzT + ((size_t)(t*16 + lr)*128 + ks*16 + lg*4));
      c = __builtin_amdgcn_mfma_f32_16x16x16bf16_1k(afr[ks], b, c, 0, 0, 0);
    }
    #pragma unroll
    for (int r = 0; r < 4; r++)
      zt[w][lg*4 + r][t*16 + lr] = __float2bfloat16(c[r]);
  }
  // coalesced zs store from the per-wave LDS tile (16 rows x 512B)
  #pragma unroll
  for (int i = 0; i < 8; i++){
    int f = i*64 + l;
    int row = f >> 5, ch = f & 31;
    int n = n0 + row;
    if (n < NN)
      *(uint4*)(zs + (size_t)n*256 + ch*8) = *(const uint4*)&zt[w][row][ch*8];
  }
}

// ---- K3a/K3b: two-level exclusive scan over 400K (node,shard) counts ----
// scan order idx = n*8 + s  (node-major -> per-node CSR ranges contiguous);
// deg8 storage is shard-major -> gathered read.
__global__ __launch_bounds__(1024) void k_scan1(const u32* __restrict__ deg8,
                                                u32* __restrict__ offs8, u32* __restrict__ bsum){
  __shared__ u32 sd[1024];
  int t = threadIdx.x;
  int i = blockIdx.x*1024 + t;
  u32 v = (i < NS) ? deg8[(size_t)(i & 7)*NN + (i >> 3)] : 0u;
  sd[t] = v; __syncthreads();
  for (int off = 1; off < 1024; off <<= 1){
    u32 u = (t >= off) ? sd[t-off] : 0u;
    __syncthreads();
    sd[t] += u;
    __syncthreads();
  }
  if (i < NS) offs8[i] = sd[t] - v;
  if (t == 1023) bsum[blockIdx.x] = sd[1023];
}

__global__ __launch_bounds__(1024) void k_scan2(u32* __restrict__ offs8,
                                                const u32* __restrict__ bsum){
  int b = blockIdx.x;
  u32 p = 0;
  for (int j = 0; j < b; j++) p += bsum[j];
  int i = b*1024 + threadIdx.x;
  if (i < NS) offs8[i] += p;
  if (i == NS-1){
    u32 tot = p;
    for (int j = b; j < NSB; j++) tot += bsum[j];
    offs8[NS] = tot;
  }
}

// ---- K4: per-edge logits + leaky_relu, CSR write with ZERO atomics ----
// csr entry uint4: {src, bf16(a0)|bf16(a1)<<16, bf16(a2)|bf16(a3)<<16, 0}
__global__ __launch_bounds__(256) void k_edge(const float* __restrict__ qraw,
        const float* __restrict__ eattr, const int* __restrict__ eidx,
        const float* __restrict__ Wq1, const float* __restrict__ bq1,
        const float* __restrict__ Wq2, const float* __restrict__ bq2,
        const float* __restrict__ Wt,
        const float* __restrict__ a_src, const float* __restrict__ a_dst,
        const u32* __restrict__ offs8, const unsigned short* __restrict__ rank,
        uint4* __restrict__ csr){
  __shared__ float sWq1[32], sbq1[8], sWq2[128], sbq2[16], sWt[64];
  int tid = threadIdx.x;
  if (tid < 32) sWq1[tid] = Wq1[tid];
  else if (tid < 40)  sbq1[tid-32]  = bq1[tid-32];
  else if (tid < 168) sWq2[tid-40]  = Wq2[tid-40];
  else if (tid < 184) sbq2[tid-168] = bq2[tid-168];
  else if (tid < 248) sWt[tid-184]  = Wt[tid-184];
  __syncthreads();
  int e = blockIdx.x*256 + tid;
  if (e >= EE) return;
  int shard = (blockIdx.x >> 2) & 7;    // == (e>>10)&7, uniform per block

  float4 qr = *(const float4*)(qraw + (size_t)e*4);
  float t1[8];
  #pragma unroll
  for (int j = 0; j < 8; j++){
    float s = sbq1[j] + qr.x*sWq1[j] + qr.y*sWq1[8+j] + qr.z*sWq1[16+j] + qr.w*sWq1[24+j];
    t1[j] = fmaxf(s, 0.f);
  }
  float ae[4] = {0.f,0.f,0.f,0.f};
  const float* ea = eattr + (size_t)e*16;
  #pragma unroll
  for (int d = 0; d < 16; d++){
    float q = sbq2[d];
    #pragma unroll
    for (int j = 0; j < 8; j++) q += t1[j]*sWq2[j*16 + d];
    float v = ea[d] + q;
    #pragma unroll
    for (int h = 0; h < 4; h++) ae[h] += v * sWt[d*4 + h];
  }
  int src = eidx[e], dst = eidx[EE + e];
  float4 as4 = *(const float4*)(a_src + (size_t)src*4);
  float4 ad4 = *(const float4*)(a_dst + (size_t)dst*4);
  float av4[4] = {as4.x + ad4.x + ae[0], as4.y + ad4.y + ae[1],
                  as4.z + ad4.z + ae[2], as4.w + ad4.w + ae[3]};
  u32 pk[4];
  #pragma unroll
  for (int hh = 0; hh < 4; hh++){
    float a = av4[hh];
    a = (a >= 0.f) ? a : NEG*a;
    pk[hh] = (u32)f2bf(a);
  }
  u32 pos = offs8[(size_t)dst*8 + shard] + (u32)rank[e];
  uint4 q;
  q.x = (u32)src;
  q.y = pk[0] | (pk[1] << 16);
  q.z = pk[2] | (pk[3] << 16);
  q.w = 0u;
  csr[pos] = q;
}

// ---- K5: per-node aggregation, no max subtraction (logits bounded), 4x unroll ----
__global__ __launch_bounds__(256) void k_agg(const __hip_bfloat16* __restrict__ zs,
        const uint4* __restrict__ csr, const u32* __restrict__ offs8,
        const float* __restrict__ cvec, float* __restrict__ out){
  int tid = threadIdx.x;
  int w = tid >> 6, lane = tid & 63;
  int n = blockIdx.x*4 + w;       // grid = NN/4 exactly
  int h = lane >> 4;              // this lane's head (channels lane*4..lane*4+3)
  u32 p0 = offs8[(size_t)n*8], p1 = offs8[(size_t)n*8 + 8];
  float d = 0.f;
  float a0 = 0.f, a1 = 0.f, a2 = 0.f, a3 = 0.f;
  u32 p = p0;
  for (; p + 4 <= p1; p += 4){
    uint4 q0 = csr[p+0], q1 = csr[p+1], q2 = csr[p+2], q3 = csr[p+3];
    u32 w0p = (h < 2) ? q0.y : q0.z,  w1p = (h < 2) ? q1.y : q1.z;
    u32 w2p = (h < 2) ? q2.y : q2.z,  w3p = (h < 2) ? q3.y : q3.z;
    int sh = (h & 1) ? 0 : 16;
    float al0 = __uint_as_float((w0p << sh) & 0xffff0000u);
    float al1 = __uint_as_float((w1p << sh) & 0xffff0000u);
    float al2 = __uint_as_float((w2p << sh) & 0xffff0000u);
    float al3 = __uint_as_float((w3p << sh) & 0xffff0000u);
    uint2 v0 = *(const uint2*)(zs + (size_t)q0.x*256 + lane*4);
    uint2 v1 = *(const uint2*)(zs + (size_t)q1.x*256 + lane*4);
    uint2 v2 = *(const uint2*)(zs + (size_t)q2.x*256 + lane*4);
    uint2 v3 = *(const uint2*)(zs + (size_t)q3.x*256 + lane*4);
    float w0 = __expf(al0), w1 = __expf(al1), w2 = __expf(al2), w3 = __expf(al3);
    a0 += w0*__uint_as_float(v0.x << 16)        + w1*__uint_as_float(v1.x << 16)
        + w2*__uint_as_float(v2.x << 16)        + w3*__uint_as_float(v3.x << 16);
    a1 += w0*__uint_as_float(v0.x & 0xffff0000u)+ w1*__uint_as_float(v1.x & 0xffff0000u)
        + w2*__uint_as_float(v2.x & 0xffff0000u)+ w3*__uint_as_float(v3.x & 0xffff0000u);
    a2 += w0*__uint_as_float(v0.y << 16)        + w1*__uint_as_float(v1.y << 16)
        + w2*__uint_as_float(v2.y << 16)        + w3*__uint_as_float(v3.y << 16);
    a3 += w0*__uint_as_float(v0.y & 0xffff0000u)+ w1*__uint_as_float(v1.y & 0xffff0000u)
        + w2*__uint_as_float(v2.y & 0xffff0000u)+ w3*__uint_as_float(v3.y & 0xffff0000u);
    d  += (w0 + w1) + (w2 + w3);
  }
  for (; p < p1; p++){
    uint4 q0 = csr[p];
    u32 w0p = (h < 2) ? q0.y : q0.z;
    int sh = (h & 1) ? 0 : 16;
    float al = __uint_as_float((w0p << sh) & 0xffff0000u);
    uint2 v0 = *(const uint2*)(zs + (size_t)q0.x*256 + lane*4);
    float w0 = __expf(al);
    a0 += w0*__uint_as_float(v0.x << 16);
    a1 += w0*__uint_as_float(v0.x & 0xffff0000u);
    a2 += w0*__uint_as_float(v0.y << 16);
    a3 += w0*__uint_as_float(v0.y & 0xffff0000u);
    d  += w0;
  }
  float inv = (d > 0.f) ? 0.25f / d : 0.f;
  a0 *= inv; a1 *= inv; a2 *= inv; a3 *= inv;
  a0 += __shfl_xor(a0, 16); a1 += __shfl_xor(a1, 16);
  a2 += __shfl_xor(a2, 16); a3 += __shfl_xor(a3, 16);
  a0 += __shfl_xor(a0, 32); a1 += __shfl_xor(a1, 32);
  a2 += __shfl_xor(a2, 32); a3 += __shfl_xor(a3, 32);
  if (lane < 16){
    float4 cv = *(const float4*)(cvec + lane*4);
    float4 o4;
    o4.x = fmaxf(a0 + cv.x, 0.f);
    o4.y = fmaxf(a1 + cv.y, 0.f);
    o4.z = fmaxf(a2 + cv.z, 0.f);
    o4.w = fmaxf(a3 + cv.w, 0.f);
    *(float4*)(out + (size_t)n*64 + lane*4) = o4;
  }
}

extern "C" void kernel_launch(void* const* d_in, const int* in_sizes, int n_in,
                              void* d_out, int out_size, void* d_ws, size_t ws_size,
                              hipStream_t stream){
  const float* x       = (const float*)d_in[0];
  const int*   eidx    = (const int*)d_in[1];
  const float* eattr   = (const float*)d_in[2];
  const float* qraw    = (const float*)d_in[3];
  const float* ns      = (const float*)d_in[4];
  const float* Wg      = (const float*)d_in[5];
  const float* att_src = (const float*)d_in[6];
  const float* att_dst = (const float*)d_in[7];
  const float* W_edge  = (const float*)d_in[8];
  const float* att_edge= (const float*)d_in[9];
  const float* b_gat   = (const float*)d_in[10];
  const float* Wq1     = (const float*)d_in[11];
  const float* bq1     = (const float*)d_in[12];
  const float* Wq2     = (const float*)d_in[13];
  const float* bq2     = (const float*)d_in[14];
  const float* W_c     = (const float*)d_in[15];
  const float* b_c     = (const float*)d_in[16];
  float* out = (float*)d_out;

  char* ws = (char*)d_ws;
  __hip_bfloat16* zs = (__hip_bfloat16*)ws;              // 0          (25,600,000)
  uint4* csr      = (uint4*)(ws + 25600000);             // 25,600,000 (12,800,000)
  u32* deg8       = (u32*)(ws + 25600000);               // ALIAS: dead before k_edge writes csr
  u32* offs8      = (u32*)(ws + 38400000);               // 38,400,000 (1,600,064)
  float* a_src    = (float*)(ws + 40000064);             //    800,000
  float* a_dst    = (float*)(ws + 40800064);             //    800,000
  unsigned short* rank = (unsigned short*)(ws + 41600064); // 1,600,000
  u32* bsum       = (u32*)(ws + 43200064);               //      2,048
  unsigned short* WzT = (unsigned short*)(ws + 43202112); //    65,536
  uint2* avp      = (uint2*)(ws + 43267648);             //      4,096
  float* Wt       = (float*)(ws + 43271744);             //        256
  float* cvec     = (float*)(ws + 43272000);             //        256

  hipMemsetAsync(deg8, 0, (size_t)NN*8*4, stream);

  k_pre_all<<<130,  256, 0, stream>>>(Wg, W_c, W_edge, att_edge, b_c, ns, b_gat,
                                      att_src, att_dst, WzT, Wt, cvec, avp);
  k_deg    <<<782,  256, 0, stream>>>(eidx + EE, deg8, rank);
  k_gemm   <<<782,  256, 0, stream>>>(x, WzT, avp, zs, a_src, a_dst);
  k_scan1  <<<NSB, 1024, 0, stream>>>(deg8, offs8, bsum);
  k_scan2  <<<NSB, 1024, 0, stream>>>(offs8, bsum);
  k_edge   <<<3125, 256, 0, stream>>>(qraw, eattr, eidx, Wq1, bq1, Wq2, bq2, Wt,
                                      a_src, a_dst, offs8, rank, csr);
  k_agg    <<<12500,256, 0, stream>>>(zs, csr, offs8, cvec, out);
}

// Round 8
// 179.218 us; speedup vs baseline: 1.3337x; 1.3337x over previous
//
#include <hip/hip_runtime.h>
#include <hip/hip_bf16.h>

#define NN 50000
#define EE 800000
#define NEG 0.2f
#define NS (NN*8)        // scan length: (node, shard) pairs
#define NSB 391          // scan blocks: ceil(400000/1024)
#define NGB 1563         // gemm blocks: ceil(NN/32)
#define NDB 782          // deg blocks:  ceil(EE/1024)

using u32 = unsigned int;
typedef short short4v __attribute__((ext_vector_type(4)));
typedef float f32x4 __attribute__((ext_vector_type(4)));

__device__ __forceinline__ unsigned short f2bf(float f){
  u32 b = __float_as_uint(f);
  b += 0x7FFFu + ((b >> 16) & 1u);        // RNE; inputs finite
  return (unsigned short)(b >> 16);
}

// ---- K0: merged precompute ----
// blocks 0..127 : WzB lane-packed bf16 B-fragments of Wz = W_gat @ blockdiag(W_c[0:64])
//                 WzB[((t*8+ks)*64 + l)*4 + q] = Wz[k][j], k=ks*16+(l>>4)*4+q, j=t*16+(l&15)
// block 128     : Wt[16][4], cvec[64] (ns-pool@W_c + b_gat@W_c + b_c folded)
// block 129     : avp[8][64] packed bf16 B-fragments (cols 0-3 src heads, 4-7 dst heads)
__global__ __launch_bounds__(256) void k_pre_all(
        const float* __restrict__ Wg, const float* __restrict__ W_c,
        const float* __restrict__ W_edge, const float* __restrict__ att_edge,
        const float* __restrict__ b_c, const float* __restrict__ ns,
        const float* __restrict__ b_gat,
        const float* __restrict__ att_src, const float* __restrict__ att_dst,
        unsigned short* __restrict__ WzB, float* __restrict__ Wt,
        float* __restrict__ cvec, uint2* __restrict__ avp){
  int bid = blockIdx.x, tid = threadIdx.x;
  if (bid < 128){
    __shared__ float sWg[256];
    __shared__ float sWc[64*64];
    sWg[tid] = Wg[bid*256 + tid];
    for (int i = tid; i < 4096; i += 256) sWc[i] = W_c[i];
    __syncthreads();
    int h = tid >> 6, j = tid & 63;
    float s = 0.f;
    #pragma unroll 8
    for (int c = 0; c < 64; c++) s += sWg[h*64 + c] * sWc[c*64 + j];
    // scatter into lane-packed fragment layout (k = bid, col j = tid)
    int t = tid >> 4, lr = tid & 15;
    int ks = bid >> 4, lg = (bid >> 2) & 3, q = bid & 3;
    int l = lg*16 + lr;
    WzB[(((t*8 + ks)*64 + l) << 2) + q] = f2bf(s);
  } else if (bid == 128){
    if (tid < 64){
      int d = tid >> 2, h = tid & 3;
      float s = 0.f;
      for (int c = 0; c < 64; c++) s += W_edge[d*256 + h*64 + c] * att_edge[h*64 + c];
      Wt[d*4 + h] = s;
    } else if (tid < 128){
      int j = tid - 64;
      float s = b_c[j];
      for (int d = 0; d < 16; d++) s += ns[d >> 1] * W_c[(64 + d)*64 + j];
      for (int c = 0; c < 64; c++) s += b_gat[c] * W_c[c*64 + j];
      cvec[j] = s;
    }
  } else {
    __shared__ float sav2[1024];       // [k][o] o: 0-3 src, 4-7 dst
    for (int i = tid; i < 1024; i += 256){
      int k = i >> 3, o = i & 7, h = o & 3;
      const float* att = (o < 4) ? att_src : att_dst;
      float s = 0.f;
      for (int c = 0; c < 64; c++) s += Wg[k*256 + h*64 + c] * att[h*64 + c];
      sav2[i] = s;
    }
    __syncthreads();
    if (tid < 64){
      int l = tid, lg = l >> 4, lr = l & 15;
      for (int ks = 0; ks < 8; ks++){
        unsigned int h0, h1, h2, h3;
        int kb = ks*16 + lg*4;
        h0 = (lr < 8) ? f2bf(sav2[(kb+0)*8 + lr]) : 0u;
        h1 = (lr < 8) ? f2bf(sav2[(kb+1)*8 + lr]) : 0u;
        h2 = (lr < 8) ? f2bf(sav2[(kb+2)*8 + lr]) : 0u;
        h3 = (lr < 8) ? f2bf(sav2[(kb+3)*8 + lr]) : 0u;
        uint2 u; u.x = h0 | (h1 << 16); u.y = h2 | (h3 << 16);
        avp[ks*64 + l] = u;
      }
    }
  }
}

// ---- K1: heterogeneous main kernel ----
// blocks [0,NGB)      : MFMA GEMM, 32 rows/block; wave = 16 rows x 8 col-tiles.
//                       Zero atomics, zero barriers, fully-coalesced B loads.
// blocks [NGB,NGB+NDB): 8-way sharded degree histogram + rank capture
//                       (overlaps GEMM tail on free CUs).
__global__ __launch_bounds__(256) void k_main(const float* __restrict__ x,
        const unsigned short* __restrict__ WzB, const uint2* __restrict__ avp,
        const int* __restrict__ dsts,
        __hip_bfloat16* __restrict__ zs,
        float* __restrict__ a_src, float* __restrict__ a_dst,
        u32* __restrict__ deg8, unsigned short* __restrict__ rank){
  __shared__ alignas(16) __hip_bfloat16 zt[4][16][136];   // per-wave private
  int tid = threadIdx.x;
  int bid = blockIdx.x;

  if (bid >= NGB){
    // ---- degree histogram path ----
    int g = bid - NGB;
    int gi = g*256 + tid;                 // group of 4 edges
    if (gi*4 < EE){
      int shard = g & 7;                  // == (e>>10)&7 for all 4 edges
      u32* dg = deg8 + (size_t)shard*NN;
      int4 d4 = *(const int4*)(dsts + (size_t)gi*4);
      u32 r0 = atomicAdd(&dg[d4.x], 1u);
      u32 r1 = atomicAdd(&dg[d4.y], 1u);
      u32 r2 = atomicAdd(&dg[d4.z], 1u);
      u32 r3 = atomicAdd(&dg[d4.w], 1u);
      uint2 pk;
      pk.x = (r0 & 0xffffu) | (r1 << 16);
      pk.y = (r2 & 0xffffu) | (r3 << 16);
      *(uint2*)(rank + (size_t)gi*4) = pk;
    }
    return;
  }

  // ---- GEMM path ----
  int w = tid >> 6, l = tid & 63;
  int lr = l & 15, lg = l >> 4;
  int rw = w >> 1, ch = w & 1;            // row-wave (0,1), col-half (0,1)
  int n0 = bid*32 + rw*16;                // wave's 16 rows

  // A-fragments (8 K-steps of 16)
  short4v afr[8];
  #pragma unroll
  for (int ks = 0; ks < 8; ks++){
    int row = n0 + lr; if (row >= NN) row = NN - 1;
    float4 xa = *(const float4*)(x + (size_t)row*128 + ks*16 + lg*4);
    short4v a;
    a[0] = (short)f2bf(xa.x); a[1] = (short)f2bf(xa.y);
    a[2] = (short)f2bf(xa.z); a[3] = (short)f2bf(xa.w);
    afr[ks] = a;
  }
  // fused a_src/a_dst MFMA (only col-half-0 waves; rows shared with twin wave)
  if (ch == 0){
    f32x4 cad = {0.f, 0.f, 0.f, 0.f};
    #pragma unroll
    for (int ks = 0; ks < 8; ks++){
      short4v b = __builtin_bit_cast(short4v, avp[ks*64 + l]);
      cad = __builtin_amdgcn_mfma_f32_16x16x16bf16_1k(afr[ks], b, cad, 0, 0, 0);
    }
    #pragma unroll
    for (int r = 0; r < 4; r++){
      int n = n0 + lg*4 + r;
      if (n < NN){
        if (lr < 4)      a_src[(size_t)n*4 + lr]       = cad[r];
        else if (lr < 8) a_dst[(size_t)n*4 + (lr - 4)] = cad[r];
      }
    }
  }

  // main GEMM: 8 column-tiles; B loads fully coalesced (512B/instr) from L1/L2
  #pragma unroll 4
  for (int t8 = 0; t8 < 8; t8++){
    int t = ch*8 + t8;
    f32x4 c = {0.f, 0.f, 0.f, 0.f};
    #pragma unroll
    for (int ks = 0; ks < 8; ks++){
      short4v b = *(const short4v*)(WzB + (((t*8 + ks)*64 + l) << 2));
      c = __builtin_amdgcn_mfma_f32_16x16x16bf16_1k(afr[ks], b, c, 0, 0, 0);
    }
    #pragma unroll
    for (int r = 0; r < 4; r++)
      zt[w][lg*4 + r][t8*16 + lr] = __float2bfloat16(c[r]);
  }
  // coalesced zs store from per-wave LDS tile (16 rows x 256B half-rows)
  #pragma unroll
  for (int i = 0; i < 4; i++){
    int f = i*64 + l;
    int row = f >> 4, c16 = f & 15;
    int n = n0 + row;
    if (n < NN)
      *(uint4*)(zs + (size_t)n*256 + ch*128 + c16*8) = *(const uint4*)&zt[w][row][c16*8];
  }
}

// ---- K3a/K3b: two-level exclusive scan over 400K (node,shard) counts ----
__global__ __launch_bounds__(1024) void k_scan1(const u32* __restrict__ deg8,
                                                u32* __restrict__ offs8, u32* __restrict__ bsum){
  __shared__ u32 sd[1024];
  int t = threadIdx.x;
  int i = blockIdx.x*1024 + t;
  u32 v = (i < NS) ? deg8[(size_t)(i & 7)*NN + (i >> 3)] : 0u;
  sd[t] = v; __syncthreads();
  for (int off = 1; off < 1024; off <<= 1){
    u32 u = (t >= off) ? sd[t-off] : 0u;
    __syncthreads();
    sd[t] += u;
    __syncthreads();
  }
  if (i < NS) offs8[i] = sd[t] - v;
  if (t == 1023) bsum[blockIdx.x] = sd[1023];
}

__global__ __launch_bounds__(1024) void k_scan2(u32* __restrict__ offs8,
                                                const u32* __restrict__ bsum){
  __shared__ u32 sd[1024];
  int b = blockIdx.x, t = threadIdx.x;
  sd[t] = (t < b) ? bsum[t] : 0u;   // NSB < 1024
  __syncthreads();
  #pragma unroll
  for (int off = 512; off; off >>= 1){
    if (t < off) sd[t] += sd[t + off];
    __syncthreads();
  }
  u32 p = sd[0];
  int i = b*1024 + t;
  if (i < NS) offs8[i] += p;
  if (b == 0 && t == 0) offs8[NS] = EE;   // grand total is known
}

// ---- K4: per-edge logits + leaky_relu, CSR write with ZERO atomics ----
// csr entry uint4: {src, bf16(a0)|bf16(a1)<<16, bf16(a2)|bf16(a3)<<16, 0}
__global__ __launch_bounds__(256) void k_edge(const float* __restrict__ qraw,
        const float* __restrict__ eattr, const int* __restrict__ eidx,
        const float* __restrict__ Wq1, const float* __restrict__ bq1,
        const float* __restrict__ Wq2, const float* __restrict__ bq2,
        const float* __restrict__ Wt,
        const float* __restrict__ a_src, const float* __restrict__ a_dst,
        const u32* __restrict__ offs8, const unsigned short* __restrict__ rank,
        uint4* __restrict__ csr){
  __shared__ float sWq1[32], sbq1[8], sWq2[128], sbq2[16], sWt[64];
  int tid = threadIdx.x;
  if (tid < 32) sWq1[tid] = Wq1[tid];
  else if (tid < 40)  sbq1[tid-32]  = bq1[tid-32];
  else if (tid < 168) sWq2[tid-40]  = Wq2[tid-40];
  else if (tid < 184) sbq2[tid-168] = bq2[tid-168];
  else if (tid < 248) sWt[tid-184]  = Wt[tid-184];
  __syncthreads();
  int e = blockIdx.x*256 + tid;
  if (e >= EE) return;
  int shard = (blockIdx.x >> 2) & 7;    // == (e>>10)&7, uniform per block

  float4 qr = *(const float4*)(qraw + (size_t)e*4);
  float t1[8];
  #pragma unroll
  for (int j = 0; j < 8; j++){
    float s = sbq1[j] + qr.x*sWq1[j] + qr.y*sWq1[8+j] + qr.z*sWq1[16+j] + qr.w*sWq1[24+j];
    t1[j] = fmaxf(s, 0.f);
  }
  float ae[4] = {0.f,0.f,0.f,0.f};
  const float* ea = eattr + (size_t)e*16;
  #pragma unroll
  for (int d = 0; d < 16; d++){
    float q = sbq2[d];
    #pragma unroll
    for (int j = 0; j < 8; j++) q += t1[j]*sWq2[j*16 + d];
    float v = ea[d] + q;
    #pragma unroll
    for (int h = 0; h < 4; h++) ae[h] += v * sWt[d*4 + h];
  }
  int src = eidx[e], dst = eidx[EE + e];
  float4 as4 = *(const float4*)(a_src + (size_t)src*4);
  float4 ad4 = *(const float4*)(a_dst + (size_t)dst*4);
  float av4[4] = {as4.x + ad4.x + ae[0], as4.y + ad4.y + ae[1],
                  as4.z + ad4.z + ae[2], as4.w + ad4.w + ae[3]};
  u32 pk[4];
  #pragma unroll
  for (int hh = 0; hh < 4; hh++){
    float a = av4[hh];
    a = (a >= 0.f) ? a : NEG*a;
    pk[hh] = (u32)f2bf(a);
  }
  u32 pos = offs8[(size_t)dst*8 + shard] + (u32)rank[e];
  uint4 q;
  q.x = (u32)src;
  q.y = pk[0] | (pk[1] << 16);
  q.z = pk[2] | (pk[3] << 16);
  q.w = 0u;
  csr[pos] = q;
}

// ---- K5: per-node aggregation, no max subtraction (logits bounded), 4x unroll ----
__global__ __launch_bounds__(256) void k_agg(const __hip_bfloat16* __restrict__ zs,
        const uint4* __restrict__ csr, const u32* __restrict__ offs8,
        const float* __restrict__ cvec, float* __restrict__ out){
  int tid = threadIdx.x;
  int w = tid >> 6, lane = tid & 63;
  int n = blockIdx.x*4 + w;       // grid = NN/4 exactly
  int h = lane >> 4;              // this lane's head (channels lane*4..lane*4+3)
  u32 p0 = offs8[(size_t)n*8], p1 = offs8[(size_t)n*8 + 8];
  float d = 0.f;
  float a0 = 0.f, a1 = 0.f, a2 = 0.f, a3 = 0.f;
  u32 p = p0;
  for (; p + 4 <= p1; p += 4){
    uint4 q0 = csr[p+0], q1 = csr[p+1], q2 = csr[p+2], q3 = csr[p+3];
    u32 w0p = (h < 2) ? q0.y : q0.z,  w1p = (h < 2) ? q1.y : q1.z;
    u32 w2p = (h < 2) ? q2.y : q2.z,  w3p = (h < 2) ? q3.y : q3.z;
    int sh = (h & 1) ? 0 : 16;
    float al0 = __uint_as_float((w0p << sh) & 0xffff0000u);
    float al1 = __uint_as_float((w1p << sh) & 0xffff0000u);
    float al2 = __uint_as_float((w2p << sh) & 0xffff0000u);
    float al3 = __uint_as_float((w3p << sh) & 0xffff0000u);
    uint2 v0 = *(const uint2*)(zs + (size_t)q0.x*256 + lane*4);
    uint2 v1 = *(const uint2*)(zs + (size_t)q1.x*256 + lane*4);
    uint2 v2 = *(const uint2*)(zs + (size_t)q2.x*256 + lane*4);
    uint2 v3 = *(const uint2*)(zs + (size_t)q3.x*256 + lane*4);
    float w0 = __expf(al0), w1 = __expf(al1), w2 = __expf(al2), w3 = __expf(al3);
    a0 += w0*__uint_as_float(v0.x << 16)        + w1*__uint_as_float(v1.x << 16)
        + w2*__uint_as_float(v2.x << 16)        + w3*__uint_as_float(v3.x << 16);
    a1 += w0*__uint_as_float(v0.x & 0xffff0000u)+ w1*__uint_as_float(v1.x & 0xffff0000u)
        + w2*__uint_as_float(v2.x & 0xffff0000u)+ w3*__uint_as_float(v3.x & 0xffff0000u);
    a2 += w0*__uint_as_float(v0.y << 16)        + w1*__uint_as_float(v1.y << 16)
        + w2*__uint_as_float(v2.y << 16)        + w3*__uint_as_float(v3.y << 16);
    a3 += w0*__uint_as_float(v0.y & 0xffff0000u)+ w1*__uint_as_float(v1.y & 0xffff0000u)
        + w2*__uint_as_float(v2.y & 0xffff0000u)+ w3*__uint_as_float(v3.y & 0xffff0000u);
    d  += (w0 + w1) + (w2 + w3);
  }
  for (; p < p1; p++){
    uint4 q0 = csr[p];
    u32 w0p = (h < 2) ? q0.y : q0.z;
    int sh = (h & 1) ? 0 : 16;
    float al = __uint_as_float((w0p << sh) & 0xffff0000u);
    uint2 v0 = *(const uint2*)(zs + (size_t)q0.x*256 + lane*4);
    float w0 = __expf(al);
    a0 += w0*__uint_as_float(v0.x << 16);
    a1 += w0*__uint_as_float(v0.x & 0xffff0000u);
    a2 += w0*__uint_as_float(v0.y << 16);
    a3 += w0*__uint_as_float(v0.y & 0xffff0000u);
    d  += w0;
  }
  float inv = (d > 0.f) ? 0.25f / d : 0.f;
  a0 *= inv; a1 *= inv; a2 *= inv; a3 *= inv;
  a0 += __shfl_xor(a0, 16); a1 += __shfl_xor(a1, 16);
  a2 += __shfl_xor(a2, 16); a3 += __shfl_xor(a3, 16);
  a0 += __shfl_xor(a0, 32); a1 += __shfl_xor(a1, 32);
  a2 += __shfl_xor(a2, 32); a3 += __shfl_xor(a3, 32);
  if (lane < 16){
    float4 cv = *(const float4*)(cvec + lane*4);
    float4 o4;
    o4.x = fmaxf(a0 + cv.x, 0.f);
    o4.y = fmaxf(a1 + cv.y, 0.f);
    o4.z = fmaxf(a2 + cv.z, 0.f);
    o4.w = fmaxf(a3 + cv.w, 0.f);
    *(float4*)(out + (size_t)n*64 + lane*4) = o4;
  }
}

extern "C" void kernel_launch(void* const* d_in, const int* in_sizes, int n_in,
                              void* d_out, int out_size, void* d_ws, size_t ws_size,
                              hipStream_t stream){
  const float* x       = (const float*)d_in[0];
  const int*   eidx    = (const int*)d_in[1];
  const float* eattr   = (const float*)d_in[2];
  const float* qraw    = (const float*)d_in[3];
  const float* ns      = (const float*)d_in[4];
  const float* Wg      = (const float*)d_in[5];
  const float* att_src = (const float*)d_in[6];
  const float* att_dst = (const float*)d_in[7];
  const float* W_edge  = (const float*)d_in[8];
  const float* att_edge= (const float*)d_in[9];
  const float* b_gat   = (const float*)d_in[10];
  const float* Wq1     = (const float*)d_in[11];
  const float* bq1     = (const float*)d_in[12];
  const float* Wq2     = (const float*)d_in[13];
  const float* bq2     = (const float*)d_in[14];
  const float* W_c     = (const float*)d_in[15];
  const float* b_c     = (const float*)d_in[16];
  float* out = (float*)d_out;

  char* ws = (char*)d_ws;
  __hip_bfloat16* zs = (__hip_bfloat16*)ws;              // 0          (25,600,000)
  uint4* csr      = (uint4*)(ws + 25600000);             // 25,600,000 (12,800,000)
  u32* deg8       = (u32*)(ws + 25600000);               // ALIAS: dead before k_edge writes csr
  u32* offs8      = (u32*)(ws + 38400000);               // 38,400,000 (1,600,064)
  float* a_src    = (float*)(ws + 40000064);             //    800,000
  float* a_dst    = (float*)(ws + 40800064);             //    800,000
  unsigned short* rank = (unsigned short*)(ws + 41600064); // 1,600,000
  u32* bsum       = (u32*)(ws + 43200064);               //      2,048
  unsigned short* WzB = (unsigned short*)(ws + 43202112); //    65,536
  uint2* avp      = (uint2*)(ws + 43267648);             //      4,096
  float* Wt       = (float*)(ws + 43271744);             //        256
  float* cvec     = (float*)(ws + 43272000);             //        256

  hipMemsetAsync(deg8, 0, (size_t)NN*8*4, stream);

  k_pre_all<<<130,      256, 0, stream>>>(Wg, W_c, W_edge, att_edge, b_c, ns, b_gat,
                                          att_src, att_dst, WzB, Wt, cvec, avp);
  k_main   <<<NGB+NDB,  256, 0, stream>>>(x, WzB, avp, eidx + EE, zs, a_src, a_dst,
                                          deg8, rank);
  k_scan1  <<<NSB,     1024, 0, stream>>>(deg8, offs8, bsum);
  k_scan2  <<<NSB,     1024, 0, stream>>>(offs8, bsum);
  k_edge   <<<3125,     256, 0, stream>>>(qraw, eattr, eidx, Wq1, bq1, Wq2, bq2, Wt,
                                          a_src, a_dst, offs8, rank, csr);
  k_agg    <<<12500,    256, 0, stream>>>(zs, csr, offs8, cvec, out);
}